// Round 5
// baseline (397.961 us; speedup 1.0000x reference)
//
#include <hip/hip_runtime.h>
#include <hip/hip_bf16.h>
#include <cstdint>

#define DIMC 192
#define BB 4
#define NN 16384
#define D3 576
#define CHD 48
#define WWID 128
#define HHGT 128
#define NCK 64          // score chunks
#define CKW 256         // cols per score chunk

typedef short short8 __attribute__((ext_vector_type(8)));
typedef float f32x4 __attribute__((ext_vector_type(4)));

union FragU { uint4 u4; short8 s8; };

// ---------- bf16 helpers ----------
__device__ __forceinline__ float bf2f(uint16_t v) {
    return __uint_as_float(((uint32_t)v) << 16);
}
__device__ __forceinline__ float2 upk2(uint32_t u) {
    float2 r;
    r.x = __uint_as_float(u << 16);
    r.y = __uint_as_float(u & 0xffff0000u);
    return r;
}
__device__ __forceinline__ uint16_t f2bf(float f) {
    uint32_t x = __float_as_uint(f);
    return (uint16_t)((x + 0x7fffu + ((x >> 16) & 1u)) >> 16);
}
__device__ __forceinline__ uint4 pack8(const uint16_t* v) {
    uint4 u;
    u.x = (uint32_t)v[0] | ((uint32_t)v[1] << 16);
    u.y = (uint32_t)v[2] | ((uint32_t)v[3] << 16);
    u.z = (uint32_t)v[4] | ((uint32_t)v[5] << 16);
    u.w = (uint32_t)v[6] | ((uint32_t)v[7] << 16);
    return u;
}

// ---------- K0: weights fp32 -> bf16 (+ folded proj_ms weights) ----------
__global__ __launch_bounds__(256) void k_prep(
    const float* __restrict__ w0, const float* __restrict__ w1,
    const float* __restrict__ w2, const float* __restrict__ w3,
    uint16_t* __restrict__ o0, uint16_t* __restrict__ o1,
    uint16_t* __restrict__ o2a, uint16_t* __restrict__ o2b,
    uint16_t* __restrict__ o3)
{
    int i = blockIdx.x * 256 + threadIdx.x;
    if (i < 110592) { o0[i] = f2bf(w0[i]); return; }
    i -= 110592;
    if (i < 110592) { o1[i] = f2bf(w1[i]); return; }
    i -= 110592;
    if (i < 36864) {
        const int o = i / DIMC, c = i % DIMC;
        o2a[i] = f2bf(w2[o * 384 + c] + w2[o * 384 + DIMC + c]);
        o2b[i] = f2bf(w2[o * 384 + DIMC + c]);
        return;
    }
    i -= 36864;
    if (i < 36864) o3[i] = f2bf(w3[i]);
}

// ---------- qkv conv1x1 MFMA: out[576][NN] = W[576][192] @ X[192][NN], bf16 out ----------
__global__ __launch_bounds__(256, 2) void k_conv_mfma(
    const float* __restrict__ x, const uint16_t* __restrict__ wbf,
    const float* __restrict__ bias, uint16_t* __restrict__ out)
{
    __shared__ uint16_t xs[128][200];
    __shared__ uint16_t wst[64][200];
    const int t = threadIdx.x;
    const int nb = blockIdx.x & 127;
    const int b = blockIdx.x >> 7;
    const int n0 = nb * 128;

    const int lane = t & 63, wvid = t >> 6;
    const int lm = lane & 15, g = lane >> 4;
    const int wm = wvid >> 1, wn = wvid & 1;
    const int wm_ = t >> 2, wq = t & 3;

    // prefetch W m-block 0 into regs (latency hidden under X staging)
    uint4 wreg[6];
    {
        const uint16_t* wrow = wbf + (size_t)wm_ * DIMC;
#pragma unroll
        for (int i = 0; i < 6; ++i)
            wreg[i] = *(const uint4*)&wrow[(i * 4 + wq) * 8];
    }
    // stage X once: fp32 -> bf16, transposed to [n][k]
    {
        const int sn = t & 127, kh = t >> 7;
        const float* xcol = x + ((size_t)b * DIMC + kh * 96) * NN + n0 + sn;
        for (int u = 0; u < 12; ++u) {
            uint16_t vals[8];
#pragma unroll
            for (int j = 0; j < 8; ++j)
                vals[j] = f2bf(xcol[(size_t)(u * 8 + j) * NN]);
            *(uint4*)&xs[sn][(kh * 12 + u) * 8] = pack8(vals);
        }
    }
#pragma unroll
    for (int i = 0; i < 6; ++i)
        *(uint4*)&wst[wm_][(i * 4 + wq) * 8] = wreg[i];
    __syncthreads();

    // hoist B fragments (reused across all 9 m-blocks)
    FragU bfr[6][4];
#pragma unroll
    for (int ks = 0; ks < 6; ++ks)
#pragma unroll
        for (int nj = 0; nj < 4; ++nj) {
            const int row = wn * 64 + nj * 16 + lm;
            bfr[ks][nj].u4 = *(const uint4*)&xs[row][ks * 32 + g * 8];
        }

    for (int mb = 0; mb < 9; ++mb) {
        // prefetch next W m-block (in flight during MFMAs below)
        if (mb < 8) {
            const uint16_t* wrow = wbf + (size_t)((mb + 1) * 64 + wm_) * DIMC;
#pragma unroll
            for (int i = 0; i < 6; ++i)
                wreg[i] = *(const uint4*)&wrow[(i * 4 + wq) * 8];
        }
        f32x4 acc[2][4];
#pragma unroll
        for (int mi = 0; mi < 2; ++mi)
#pragma unroll
            for (int nj = 0; nj < 4; ++nj) acc[mi][nj] = (f32x4){0.f, 0.f, 0.f, 0.f};
#pragma unroll
        for (int ks = 0; ks < 6; ++ks) {
            FragU afr[2];
#pragma unroll
            for (int mi = 0; mi < 2; ++mi) {
                const int row = wm * 32 + mi * 16 + lm;
                afr[mi].u4 = *(const uint4*)&wst[row][ks * 32 + g * 8];
            }
#pragma unroll
            for (int mi = 0; mi < 2; ++mi)
#pragma unroll
                for (int nj = 0; nj < 4; ++nj)
                    acc[mi][nj] = __builtin_amdgcn_mfma_f32_16x16x32_bf16(
                        afr[mi].s8, bfr[ks][nj].s8, acc[mi][nj], 0, 0, 0);
        }
        // epilogue for this m-block
#pragma unroll
        for (int mi = 0; mi < 2; ++mi) {
            const int rbase = mb * 64 + wm * 32 + mi * 16 + g * 4;
            const float4 bv = *(const float4*)&bias[rbase];
            const float bva[4] = {bv.x, bv.y, bv.z, bv.w};
#pragma unroll
            for (int nj = 0; nj < 4; ++nj) {
                const int gcol = n0 + wn * 64 + nj * 16 + lm;
#pragma unroll
                for (int r = 0; r < 4; ++r)
                    out[((size_t)b * D3 + rbase + r) * NN + gcol] =
                        f2bf(acc[mi][nj][r] + bva[r]);
            }
        }
        if (mb < 8) {
            __syncthreads();
#pragma unroll
            for (int i = 0; i < 6; ++i)
                *(uint4*)&wst[wm_][(i * 4 + wq) * 8] = wreg[i];
            __syncthreads();
        }
    }
}

// ---------- proj MFMA: out[192][NN] = sum_ph W_ph[192][192] @ X_ph[192][NN] + resid ----------
template<int PHASES>
__global__ __launch_bounds__(256, 2) void k_proj_mfma(
    const uint16_t* __restrict__ x0, const uint16_t* __restrict__ x1,
    const uint16_t* __restrict__ w0, const uint16_t* __restrict__ w1,
    const float* __restrict__ bias, const float* __restrict__ resid,
    float* __restrict__ out)
{
    __shared__ uint16_t xs[128][200];
    __shared__ uint16_t wst[64][200];
    const int t = threadIdx.x;
    const int nb = blockIdx.x & 127;
    const int b = blockIdx.x >> 7;
    const int n0 = nb * 128;

    const int lane = t & 63, wvid = t >> 6;
    const int lm = lane & 15, g = lane >> 4;
    const int wm = wvid >> 1, wn = wvid & 1;
    const int wm_ = t >> 2, wq = t & 3;

    f32x4 acc[3][2][4];
#pragma unroll
    for (int mb = 0; mb < 3; ++mb)
#pragma unroll
        for (int mi = 0; mi < 2; ++mi)
#pragma unroll
            for (int nj = 0; nj < 4; ++nj) acc[mb][mi][nj] = (f32x4){0.f, 0.f, 0.f, 0.f};

    for (int ph = 0; ph < PHASES; ++ph) {
        const uint16_t* xsrc = ph ? x1 : x0;
        const uint16_t* wsrc = ph ? w1 : w0;
        if (ph) __syncthreads();
        uint4 wreg[6];
        {
            const uint16_t* wrow = wsrc + (size_t)wm_ * DIMC;
#pragma unroll
            for (int i = 0; i < 6; ++i)
                wreg[i] = *(const uint4*)&wrow[(i * 4 + wq) * 8];
        }
        // stage X (bf16, transpose to [n][k])
        {
            const int sn = t & 127, kh = t >> 7;
            const uint16_t* xcol = xsrc + ((size_t)b * DIMC + kh * 96) * NN + n0 + sn;
            for (int u = 0; u < 12; ++u) {
                uint16_t vals[8];
#pragma unroll
                for (int j = 0; j < 8; ++j)
                    vals[j] = xcol[(size_t)(u * 8 + j) * NN];
                *(uint4*)&xs[sn][(kh * 12 + u) * 8] = pack8(vals);
            }
        }
#pragma unroll
        for (int i = 0; i < 6; ++i)
            *(uint4*)&wst[wm_][(i * 4 + wq) * 8] = wreg[i];
        __syncthreads();
        FragU bfr[6][4];
#pragma unroll
        for (int ks = 0; ks < 6; ++ks)
#pragma unroll
            for (int nj = 0; nj < 4; ++nj) {
                const int row = wn * 64 + nj * 16 + lm;
                bfr[ks][nj].u4 = *(const uint4*)&xs[row][ks * 32 + g * 8];
            }
        for (int mb = 0; mb < 3; ++mb) {
            if (mb < 2) {
                const uint16_t* wrow = wsrc + (size_t)((mb + 1) * 64 + wm_) * DIMC;
#pragma unroll
                for (int i = 0; i < 6; ++i)
                    wreg[i] = *(const uint4*)&wrow[(i * 4 + wq) * 8];
            }
#pragma unroll
            for (int ks = 0; ks < 6; ++ks) {
                FragU afr[2];
#pragma unroll
                for (int mi = 0; mi < 2; ++mi) {
                    const int row = wm * 32 + mi * 16 + lm;
                    afr[mi].u4 = *(const uint4*)&wst[row][ks * 32 + g * 8];
                }
#pragma unroll
                for (int mi = 0; mi < 2; ++mi)
#pragma unroll
                    for (int nj = 0; nj < 4; ++nj)
                        acc[mb][mi][nj] = __builtin_amdgcn_mfma_f32_16x16x32_bf16(
                            afr[mi].s8, bfr[ks][nj].s8, acc[mb][mi][nj], 0, 0, 0);
            }
            if (mb < 2) {
                __syncthreads();
#pragma unroll
                for (int i = 0; i < 6; ++i)
                    *(uint4*)&wst[wm_][(i * 4 + wq) * 8] = wreg[i];
                __syncthreads();
            }
        }
    }
    // epilogue: bias + residual, fp32 out
#pragma unroll
    for (int mb = 0; mb < 3; ++mb)
#pragma unroll
        for (int mi = 0; mi < 2; ++mi) {
            const int rbase = mb * 64 + wm * 32 + mi * 16 + g * 4;
            const float4 bv = *(const float4*)&bias[rbase];
            const float bva[4] = {bv.x, bv.y, bv.z, bv.w};
#pragma unroll
            for (int nj = 0; nj < 4; ++nj) {
                const int gcol = n0 + wn * 64 + nj * 16 + lm;
#pragma unroll
                for (int r = 0; r < 4; ++r) {
                    const size_t idx = ((size_t)b * DIMC + rbase + r) * NN + gcol;
                    out[idx] = resid[idx] + acc[mb][mi][nj][r] + bva[r];
                }
            }
        }
}

// ---------- depthwise 3x3 + bias, 8 px/thread ----------
__global__ __launch_bounds__(256) void k_dwconv2(
    const uint16_t* __restrict__ in, const float* __restrict__ w9,
    const float* __restrict__ bias, uint16_t* __restrict__ out)
{
    const int t = threadIdx.x;
    const int bc = blockIdx.z;
    const int ch = bc % D3;
    const int xg = t & 15, yl = t >> 4;
    const int x0 = xg * 8;
    const int y = blockIdx.y * 16 + yl;
    const uint16_t* p = in + (size_t)bc * NN;
    float wv[9];
#pragma unroll
    for (int k = 0; k < 9; ++k) wv[k] = w9[ch * 9 + k];
    float r[3][10];
#pragma unroll
    for (int dy = 0; dy < 3; ++dy) {
        const int yy = y + dy - 1;
        if (yy < 0 || yy >= HHGT) {
#pragma unroll
            for (int j = 0; j < 10; ++j) r[dy][j] = 0.f;
        } else {
            const uint16_t* row = p + yy * WWID;
            uint4 u = *(const uint4*)(row + x0);
            const uint16_t* pv = (const uint16_t*)&u;
#pragma unroll
            for (int j = 0; j < 8; ++j) r[dy][j + 1] = bf2f(pv[j]);
            r[dy][0] = (x0 > 0) ? bf2f(row[x0 - 1]) : 0.f;
            r[dy][9] = (x0 + 8 < WWID) ? bf2f(row[x0 + 8]) : 0.f;
        }
    }
    const float base = bias[ch];
    uint16_t ov[8];
#pragma unroll
    for (int j = 0; j < 8; ++j) {
        float a = base;
#pragma unroll
        for (int dy = 0; dy < 3; ++dy)
#pragma unroll
            for (int dx = 0; dx < 3; ++dx)
                a = fmaf(r[dy][j + dx], wv[dy * 3 + dx], a);
        ov[j] = f2bf(a);
    }
    *(uint4*)(out + (size_t)bc * NN + y * WWID + x0) = pack8(ov);
}

// ---------- MFMA scores + fused norm partials ----------
// grid = 16 pid (b*4+h) x 64 chunks of 256 cols. Waves 0-2: one Gram each
// (0=ms_self, 1=sar_self, 2=cross). Wave 3: sumsq partials (replaces k_norms).
__global__ __launch_bounds__(256) void k_scores_mfma(
    const uint16_t* __restrict__ qkv_ms, const uint16_t* __restrict__ qkv_sar,
    float* __restrict__ partial, float* __restrict__ sumsq)
{
    const int t = threadIdx.x;
    const int bid = blockIdx.x;
    const int ck = bid & (NCK - 1);
    const int pid = bid / NCK;         // b*4 + h
    const int h = pid & 3, b = pid >> 2;
    const int n0 = ck * CKW;
    const int lane = t & 63, w = t >> 6;

    const uint16_t* qm  = qkv_ms  + ((size_t)b * D3 + h * CHD) * NN;
    const uint16_t* km  = qkv_ms  + ((size_t)b * D3 + DIMC + h * CHD) * NN;
    const uint16_t* qsr = qkv_sar + ((size_t)b * D3 + h * CHD) * NN;
    const uint16_t* ksr = qkv_sar + ((size_t)b * D3 + DIMC + h * CHD) * NN;

    if (w < 3) {
        const uint16_t* qb = (w == 0) ? qm : qsr;
        const uint16_t* kb = (w == 1) ? ksr : km;
        const int lm = lane & 15, g = lane >> 4;
        f32x4 acc[3][3];
#pragma unroll
        for (int i = 0; i < 3; ++i)
#pragma unroll
            for (int j = 0; j < 3; ++j) acc[i][j] = (f32x4){0.f, 0.f, 0.f, 0.f};
#pragma unroll 2
        for (int kk = 0; kk < CKW / 32; ++kk) {
            const int nb2 = n0 + kk * 32 + g * 8;
            FragU qf[3], kf[3];
#pragma unroll
            for (int i = 0; i < 3; ++i)
                qf[i].u4 = *(const uint4*)&qb[(size_t)(i * 16 + lm) * NN + nb2];
#pragma unroll
            for (int j = 0; j < 3; ++j)
                kf[j].u4 = *(const uint4*)&kb[(size_t)(j * 16 + lm) * NN + nb2];
#pragma unroll
            for (int i = 0; i < 3; ++i)
#pragma unroll
                for (int j = 0; j < 3; ++j)
                    acc[i][j] = __builtin_amdgcn_mfma_f32_16x16x32_bf16(
                        qf[i].s8, kf[j].s8, acc[i][j], 0, 0, 0);
        }
        float* pd = partial + (((size_t)pid * 3 + w) * NCK + ck) * 2304;
        const int g4 = g * 4;
#pragma unroll
        for (int i = 0; i < 3; ++i)
#pragma unroll
            for (int j = 0; j < 3; ++j)
#pragma unroll
                for (int r = 0; r < 4; ++r)
                    pd[(i * 16 + g4 + r) * 48 + j * 16 + lm] = acc[i][j][r];
    } else {
        // sumsq of 192 rows (0=q_ms 1=k_ms 2=q_sar 3=k_sar) over this chunk
#pragma unroll
        for (int rep = 0; rep < 3; ++rep) {
            const int rid = rep * 64 + lane;
            const int s = rid / CHD, c = rid % CHD;
            const uint16_t* rowp =
                (s == 0) ? qm  + (size_t)c * NN :
                (s == 1) ? km  + (size_t)c * NN :
                (s == 2) ? qsr + (size_t)c * NN :
                           ksr + (size_t)c * NN;
            float sum = 0.f;
#pragma unroll 4
            for (int u = 0; u < CKW / 8; ++u) {
                uint4 v = *(const uint4*)&rowp[n0 + u * 8];
                uint32_t uu[4] = {v.x, v.y, v.z, v.w};
#pragma unroll
                for (int q = 0; q < 4; ++q) {
                    float2 f = upk2(uu[q]);
                    sum = fmaf(f.x, f.x, fmaf(f.y, f.y, sum));
                }
            }
            sumsq[(((size_t)pid * NCK + ck) * 4 + s) * CHD + c] = sum;
        }
    }
}

// ---------- reduce chunks + norm scale + softmax ----------
__global__ __launch_bounds__(64) void k_softmax(
    const float* __restrict__ partial, const float* __restrict__ sumsq,
    const float* __restrict__ ms_temp, const float* __restrict__ sar_temp,
    float* __restrict__ A)
{
    const int lane = threadIdx.x;
    const int bi = blockIdx.x;
    const int c = bi % 48;
    const int pid = bi / 48;               // type*16 + b*4 + h
    const int h = pid & 3, b = (pid >> 2) & 3, type = pid >> 4;
    const int pid16 = b * 4 + h;
    float s;
    if (lane < 48) {
        float accv = 0.f;
        const float* pp = partial + ((size_t)pid16 * 3 + type) * NCK * 2304 + c * 48 + lane;
#pragma unroll 8
        for (int ck = 0; ck < NCK; ++ck) accv += pp[(size_t)ck * 2304];
        const int qset = (type == 0) ? 0 : 2;
        const int kset = (type == 1) ? 3 : 1;
        float qsum = 0.f, ksum = 0.f;
        const float* sq = sumsq + (size_t)pid16 * NCK * 4 * CHD;
#pragma unroll 8
        for (int ck = 0; ck < NCK; ++ck) {
            qsum += sq[ck * 4 * CHD + qset * CHD + c];
            ksum += sq[ck * 4 * CHD + kset * CHD + lane];
        }
        const float tval = (type == 1) ? sar_temp[h] : ms_temp[h];
        const float qsc = 1.0f / fmaxf(sqrtf(qsum), 1e-12f);
        const float ksc = 1.0f / fmaxf(sqrtf(ksum), 1e-12f);
        s = accv * qsc * ksc * tval;
    } else {
        s = -3.0e38f;
    }
    float m = s;
#pragma unroll
    for (int o = 32; o > 0; o >>= 1) m = fmaxf(m, __shfl_xor(m, o));
    float e = (lane < 48) ? __expf(s - m) : 0.f;
    float sum = e;
#pragma unroll
    for (int o = 32; o > 0; o >>= 1) sum += __shfl_xor(sum, o);
    if (lane < 48) A[(size_t)pid * 2304 + c * 48 + lane] = e / sum;
}

// ---------- MFMA apply: out[c][n] = sum_d A[c][d] V[d][n] ----------
__global__ __launch_bounds__(256) void k_apply_mfma(
    const float* __restrict__ A, const uint16_t* __restrict__ qkv_ms,
    const uint16_t* __restrict__ qkv_sar, uint16_t* __restrict__ attn)
{
    __shared__ uint16_t vs[256][40];
    __shared__ uint16_t as[48][40];
    const int t = threadIdx.x;
    const int nb = blockIdx.x & 63;
    const int pid = blockIdx.x >> 6;
    const int h = pid & 3, b = (pid >> 2) & 3, type = pid >> 4;
    const int n0 = nb * 256;
    const uint16_t* vsrc = (type == 0) ? qkv_ms : qkv_sar;
    const uint16_t* vb = vsrc + ((size_t)b * D3 + 2 * DIMC + (size_t)h * CHD) * NN;
    const float* Ap = A + (size_t)pid * 2304;

    const int lane = t & 63, wvid = t >> 6;
    const int lm = lane & 15, g = lane >> 4;

    f32x4 acc[3][4];
#pragma unroll
    for (int i = 0; i < 3; ++i)
#pragma unroll
        for (int j = 0; j < 4; ++j) acc[i][j] = (f32x4){0.f, 0.f, 0.f, 0.f};

    for (int k0 = 0; k0 < 64; k0 += 32) {
        __syncthreads();
#pragma unroll
        for (int kh = 0; kh < 2; ++kh) {
            uint16_t vals[16];
#pragma unroll
            for (int j = 0; j < 16; ++j) {
                const int d = k0 + kh * 16 + j;
                vals[j] = (d < CHD) ? vb[(size_t)d * NN + n0 + t] : (uint16_t)0;
            }
            const int u0 = (2 * kh) ^ ((t >> 3) & 3);
            const int u1 = (2 * kh + 1) ^ ((t >> 3) & 3);
            *(uint4*)&vs[t][u0 * 8] = pack8(&vals[0]);
            *(uint4*)&vs[t][u1 * 8] = pack8(&vals[8]);
        }
        if (t < 192) {
            const int c = t >> 2, dq = t & 3;
            uint16_t av[8];
#pragma unroll
            for (int i = 0; i < 8; ++i) {
                const int d = k0 + dq * 8 + i;
                av[i] = (d < CHD) ? f2bf(Ap[c * CHD + d]) : (uint16_t)0;
            }
            const int u = dq ^ ((c >> 3) & 3);
            *(uint4*)&as[c][u * 8] = pack8(av);
        }
        __syncthreads();
        FragU afr[3], bfr[4];
#pragma unroll
        for (int mi = 0; mi < 3; ++mi) {
            const int row = mi * 16 + lm;
            afr[mi].u4 = *(const uint4*)&as[row][(g ^ ((row >> 3) & 3)) * 8];
        }
#pragma unroll
        for (int nj = 0; nj < 4; ++nj) {
            const int row = wvid * 64 + nj * 16 + lm;
            bfr[nj].u4 = *(const uint4*)&vs[row][(g ^ ((row >> 3) & 3)) * 8];
        }
#pragma unroll
        for (int mi = 0; mi < 3; ++mi)
#pragma unroll
            for (int nj = 0; nj < 4; ++nj)
                acc[mi][nj] = __builtin_amdgcn_mfma_f32_16x16x32_bf16(
                    afr[mi].s8, bfr[nj].s8, acc[mi][nj], 0, 0, 0);
    }

    uint16_t* ob = attn + (size_t)type * BB * DIMC * NN +
                   ((size_t)b * DIMC + (size_t)h * CHD) * NN;
#pragma unroll
    for (int mi = 0; mi < 3; ++mi) {
        const int rbase = mi * 16 + g * 4;
#pragma unroll
        for (int nj = 0; nj < 4; ++nj) {
            const int gcol = n0 + wvid * 64 + nj * 16 + lm;
#pragma unroll
            for (int r = 0; r < 4; ++r)
                ob[(size_t)(rbase + r) * NN + gcol] = f2bf(acc[mi][nj][r]);
        }
    }
}

extern "C" void kernel_launch(void* const* d_in, const int* in_sizes, int n_in,
                              void* d_out, int out_size, void* d_ws, size_t ws_size,
                              hipStream_t stream)
{
    const float* sar        = (const float*)d_in[0];
    const float* ms         = (const float*)d_in[1];
    const float* ms_qkv_w   = (const float*)d_in[2];
    const float* ms_qkv_b   = (const float*)d_in[3];
    const float* ms_dw_w    = (const float*)d_in[4];
    const float* ms_dw_b    = (const float*)d_in[5];
    const float* ms_temp    = (const float*)d_in[6];
    const float* sar_qkv_w  = (const float*)d_in[7];
    const float* sar_qkv_b  = (const float*)d_in[8];
    const float* sar_dw_w   = (const float*)d_in[9];
    const float* sar_dw_b   = (const float*)d_in[10];
    const float* sar_temp   = (const float*)d_in[11];
    const float* ms_proj_w  = (const float*)d_in[12];
    const float* ms_proj_b  = (const float*)d_in[13];
    const float* sar_proj_w = (const float*)d_in[14];
    const float* sar_proj_b = (const float*)d_in[15];

    char* ws = (char*)d_ws;
    // ws layout (bytes):
    //   [0,          75497472)  tmp bf16 (conv1x1 out) -> score partials scratch
    //                           -> finally attn outputs (written by apply)
    //     partial: 16pid x 3type x 64ck x 2304 f32 = 28.3 MB at +0
    //     sumsq:   16pid x 64ck x 4set x 48  f32 = 0.79 MB at +32MB
    //   [75497472,  150994944)  qkv_ms bf16
    //   [150994944, 226492416)  qkv_sar bf16
    //   [230043648, 230486016)  softmaxed A f32
    //   [230486016, 231149568)  bf16 weights
    uint16_t* tmp     = (uint16_t*)(ws);
    uint16_t* qkv_ms  = (uint16_t*)(ws + 75497472ull);
    uint16_t* qkv_sar = (uint16_t*)(ws + 150994944ull);
    float* partial    = (float*)(ws);
    float* sumsq      = (float*)(ws + 33554432ull);
    float* Amat       = (float*)(ws + 230043648ull);
    uint16_t* wq_ms   = (uint16_t*)(ws + 230486016ull);
    uint16_t* wq_sar  = (uint16_t*)(ws + 230707200ull);
    uint16_t* wp1_ms  = (uint16_t*)(ws + 230928384ull);
    uint16_t* wp2_ms  = (uint16_t*)(ws + 231002112ull);
    uint16_t* wp_sar  = (uint16_t*)(ws + 231075840ull);
    uint16_t* attn    = tmp;

    float* out_sar = (float*)d_out;
    float* out_ms  = out_sar + (size_t)BB * DIMC * NN;

    dim3 b256(256);
    k_prep<<<dim3(1152), b256, 0, stream>>>(ms_qkv_w, sar_qkv_w, ms_proj_w, sar_proj_w,
                                            wq_ms, wq_sar, wp1_ms, wp2_ms, wp_sar);
    k_conv_mfma<<<dim3(128 * BB), b256, 0, stream>>>(ms, wq_ms, ms_qkv_b, tmp);
    k_dwconv2<<<dim3(1, 8, BB * D3), b256, 0, stream>>>(tmp, ms_dw_w, ms_dw_b, qkv_ms);
    k_conv_mfma<<<dim3(128 * BB), b256, 0, stream>>>(sar, wq_sar, sar_qkv_b, tmp);
    k_dwconv2<<<dim3(1, 8, BB * D3), b256, 0, stream>>>(tmp, sar_dw_w, sar_dw_b, qkv_sar);

    k_scores_mfma<<<dim3(16 * NCK), b256, 0, stream>>>(qkv_ms, qkv_sar, partial, sumsq);
    k_softmax<<<dim3(48 * 48), dim3(64), 0, stream>>>(partial, sumsq, ms_temp, sar_temp, Amat);
    k_apply_mfma<<<dim3(48 * 64), b256, 0, stream>>>(Amat, qkv_ms, qkv_sar, attn);

    uint16_t* ms_self  = attn;
    uint16_t* sar_self = attn + (size_t)BB * DIMC * NN;
    uint16_t* crossb   = attn + 2ull * BB * DIMC * NN;
    k_proj_mfma<1><<<dim3(128 * BB), b256, 0, stream>>>(
        sar_self, nullptr, wp_sar, nullptr, sar_proj_b, sar, out_sar);
    k_proj_mfma<2><<<dim3(128 * BB), b256, 0, stream>>>(
        ms_self, crossb, wp1_ms, wp2_ms, ms_proj_b, ms, out_ms);
}

// Round 6
// 312.051 us; speedup vs baseline: 1.2753x; 1.2753x over previous
//
#include <hip/hip_runtime.h>
#include <hip/hip_bf16.h>
#include <cstdint>

#define DIMC 192
#define BB 4
#define NN 16384
#define D3 576
#define CHD 48
#define WWID 128
#define HHGT 128
#define NCK 64          // score chunks
#define CKW 256         // cols per score chunk

typedef short short8 __attribute__((ext_vector_type(8)));
typedef float f32x4 __attribute__((ext_vector_type(4)));

union FragU { uint4 u4; short8 s8; };

// ---------- bf16 helpers ----------
__device__ __forceinline__ float bf2f(uint16_t v) {
    return __uint_as_float(((uint32_t)v) << 16);
}
__device__ __forceinline__ float2 upk2(uint32_t u) {
    float2 r;
    r.x = __uint_as_float(u << 16);
    r.y = __uint_as_float(u & 0xffff0000u);
    return r;
}
__device__ __forceinline__ uint16_t f2bf(float f) {
    uint32_t x = __float_as_uint(f);
    return (uint16_t)((x + 0x7fffu + ((x >> 16) & 1u)) >> 16);
}
__device__ __forceinline__ uint4 pack8(const uint16_t* v) {
    uint4 u;
    u.x = (uint32_t)v[0] | ((uint32_t)v[1] << 16);
    u.y = (uint32_t)v[2] | ((uint32_t)v[3] << 16);
    u.z = (uint32_t)v[4] | ((uint32_t)v[5] << 16);
    u.w = (uint32_t)v[6] | ((uint32_t)v[7] << 16);
    return u;
}

// ---------- K0: weights fp32 -> bf16 (+ folded proj_ms weights) ----------
__global__ __launch_bounds__(256) void k_prep(
    const float* __restrict__ w0, const float* __restrict__ w1,
    const float* __restrict__ w2, const float* __restrict__ w3,
    uint16_t* __restrict__ o0, uint16_t* __restrict__ o1,
    uint16_t* __restrict__ o2a, uint16_t* __restrict__ o2b,
    uint16_t* __restrict__ o3)
{
    int i = blockIdx.x * 256 + threadIdx.x;
    if (i < 110592) { o0[i] = f2bf(w0[i]); return; }
    i -= 110592;
    if (i < 110592) { o1[i] = f2bf(w1[i]); return; }
    i -= 110592;
    if (i < 36864) {
        const int o = i / DIMC, c = i % DIMC;
        o2a[i] = f2bf(w2[o * 384 + c] + w2[o * 384 + DIMC + c]);
        o2b[i] = f2bf(w2[o * 384 + DIMC + c]);
        return;
    }
    i -= 36864;
    if (i < 36864) o3[i] = f2bf(w3[i]);
}

// ---------- qkv conv1x1 MFMA: out[576][NN] = W[576][192] @ X[192][NN], bf16 out ----------
// Round-3 staging structure (measured good); NEW: coalesced epilogue via
// wave-private LDS scratch carved from xs (dead after fragment hoist).
__global__ __launch_bounds__(256, 2) void k_conv_mfma(
    const float* __restrict__ x, const uint16_t* __restrict__ wbf,
    const float* __restrict__ bias, uint16_t* __restrict__ out)
{
    __shared__ uint16_t xs[128][200];   // [n][k]; reused as store scratch later
    __shared__ uint16_t wst[64][200];   // [m][k]
    const int t = threadIdx.x;
    const int nb = blockIdx.x & 127;
    const int b = blockIdx.x >> 7;
    const int n0 = nb * 128;

    const int lane = t & 63, wvid = t >> 6;
    const int lm = lane & 15, g = lane >> 4;
    const int wm = wvid >> 1, wn = wvid & 1;

    // ---- stage X once: fp32 -> bf16, transposed to [n][k] ----
    {
        const int sn = t & 127, kh = t >> 7;
        const float* xcol = x + ((size_t)b * DIMC + kh * 96) * NN + n0 + sn;
        for (int u = 0; u < 12; ++u) {
            uint16_t vals[8];
#pragma unroll
            for (int j = 0; j < 8; ++j)
                vals[j] = f2bf(xcol[(size_t)(u * 8 + j) * NN]);
            *(uint4*)&xs[sn][(kh * 12 + u) * 8] = pack8(vals);
        }
    }
    // ---- stage W m-block 0 ----
    {
        const int wm_ = t >> 2, wq = t & 3;
        const uint16_t* wrow = wbf + (size_t)wm_ * DIMC;
#pragma unroll
        for (int i = 0; i < 6; ++i) {
            const int unit = i * 4 + wq;
            *(uint4*)&wst[wm_][unit * 8] = *(const uint4*)&wrow[unit * 8];
        }
    }
    __syncthreads();

    // ---- hoist B fragments (reused across all 9 m-blocks) ----
    FragU bfr[6][4];
#pragma unroll
    for (int ks = 0; ks < 6; ++ks)
#pragma unroll
        for (int nj = 0; nj < 4; ++nj) {
            const int row = wn * 64 + nj * 16 + lm;
            bfr[ks][nj].u4 = *(const uint4*)&xs[row][ks * 32 + g * 8];
        }
    __syncthreads();   // all waves done reading xs -> safe to reuse as scratch

    uint16_t* sw = &xs[0][0] + wvid * (32 * 72);  // wave-private 32x72 u16

    for (int mb = 0; mb < 9; ++mb) {
        if (mb) {
            __syncthreads();
            const int wm_ = t >> 2, wq = t & 3;
            const uint16_t* wrow = wbf + (size_t)(mb * 64 + wm_) * DIMC;
#pragma unroll
            for (int i = 0; i < 6; ++i) {
                const int unit = i * 4 + wq;
                *(uint4*)&wst[wm_][unit * 8] = *(const uint4*)&wrow[unit * 8];
            }
            __syncthreads();
        }
        f32x4 acc[2][4];
#pragma unroll
        for (int mi = 0; mi < 2; ++mi)
#pragma unroll
            for (int nj = 0; nj < 4; ++nj) acc[mi][nj] = (f32x4){0.f, 0.f, 0.f, 0.f};
#pragma unroll
        for (int ks = 0; ks < 6; ++ks) {
            FragU afr[2];
#pragma unroll
            for (int mi = 0; mi < 2; ++mi) {
                const int row = wm * 32 + mi * 16 + lm;
                afr[mi].u4 = *(const uint4*)&wst[row][ks * 32 + g * 8];
            }
#pragma unroll
            for (int mi = 0; mi < 2; ++mi)
#pragma unroll
                for (int nj = 0; nj < 4; ++nj)
                    acc[mi][nj] = __builtin_amdgcn_mfma_f32_16x16x32_bf16(
                        afr[mi].s8, bfr[ks][nj].s8, acc[mi][nj], 0, 0, 0);
        }
        // ---- epilogue: acc -> wave-private LDS -> coalesced 16B stores ----
#pragma unroll
        for (int mi = 0; mi < 2; ++mi) {
            const int rbase = mb * 64 + wm * 32 + mi * 16 + g * 4;
            const float4 bv = *(const float4*)&bias[rbase];
            const float bva[4] = {bv.x, bv.y, bv.z, bv.w};
#pragma unroll
            for (int nj = 0; nj < 4; ++nj)
#pragma unroll
                for (int r = 0; r < 4; ++r)
                    sw[(mi * 16 + g * 4 + r) * 72 + nj * 16 + lm] =
                        f2bf(acc[mi][nj][r] + bva[r]);
        }
        const int l8 = lane & 7, r8 = lane >> 3;
#pragma unroll
        for (int pass = 0; pass < 4; ++pass) {
            const int rr = pass * 8 + r8;
            uint4 v = *(const uint4*)&sw[rr * 72 + l8 * 8];
            const int grow = mb * 64 + wm * 32 + rr;
            *(uint4*)&out[((size_t)b * D3 + grow) * NN + n0 + wn * 64 + l8 * 8] = v;
        }
    }
}

// ---------- proj MFMA: out[192][NN] = sum_ph W_ph[192][192] @ X_ph[192][NN] + resid ----------
// (round-3 structure, reverted)
template<int PHASES>
__global__ __launch_bounds__(256, 2) void k_proj_mfma(
    const uint16_t* __restrict__ x0, const uint16_t* __restrict__ x1,
    const uint16_t* __restrict__ w0, const uint16_t* __restrict__ w1,
    const float* __restrict__ bias, const float* __restrict__ resid,
    float* __restrict__ out)
{
    __shared__ uint16_t xs[128][200];
    __shared__ uint16_t wst[64][200];
    const int t = threadIdx.x;
    const int nb = blockIdx.x & 127;
    const int b = blockIdx.x >> 7;
    const int n0 = nb * 128;

    const int lane = t & 63, wvid = t >> 6;
    const int lm = lane & 15, g = lane >> 4;
    const int wm = wvid >> 1, wn = wvid & 1;

    f32x4 acc[3][2][4];
#pragma unroll
    for (int mb = 0; mb < 3; ++mb)
#pragma unroll
        for (int mi = 0; mi < 2; ++mi)
#pragma unroll
            for (int nj = 0; nj < 4; ++nj) acc[mb][mi][nj] = (f32x4){0.f, 0.f, 0.f, 0.f};

    for (int ph = 0; ph < PHASES; ++ph) {
        const uint16_t* xsrc = ph ? x1 : x0;
        const uint16_t* wsrc = ph ? w1 : w0;
        if (ph) __syncthreads();
        // stage X (bf16, transpose to [n][k])
        {
            const int sn = t & 127, kh = t >> 7;
            const uint16_t* xcol = xsrc + ((size_t)b * DIMC + kh * 96) * NN + n0 + sn;
            for (int u = 0; u < 12; ++u) {
                uint16_t vals[8];
#pragma unroll
                for (int j = 0; j < 8; ++j)
                    vals[j] = xcol[(size_t)(u * 8 + j) * NN];
                *(uint4*)&xs[sn][(kh * 12 + u) * 8] = pack8(vals);
            }
        }
        // stage W m-block 0
        {
            const int wm_ = t >> 2, wq = t & 3;
            const uint16_t* wrow = wsrc + (size_t)wm_ * DIMC;
#pragma unroll
            for (int i = 0; i < 6; ++i) {
                const int unit = i * 4 + wq;
                *(uint4*)&wst[wm_][unit * 8] = *(const uint4*)&wrow[unit * 8];
            }
        }
        __syncthreads();
        FragU bfr[6][4];
#pragma unroll
        for (int ks = 0; ks < 6; ++ks)
#pragma unroll
            for (int nj = 0; nj < 4; ++nj) {
                const int row = wn * 64 + nj * 16 + lm;
                bfr[ks][nj].u4 = *(const uint4*)&xs[row][ks * 32 + g * 8];
            }
        for (int mb = 0; mb < 3; ++mb) {
            if (mb) {
                __syncthreads();
                const int wm_ = t >> 2, wq = t & 3;
                const uint16_t* wrow = wsrc + (size_t)(mb * 64 + wm_) * DIMC;
#pragma unroll
                for (int i = 0; i < 6; ++i) {
                    const int unit = i * 4 + wq;
                    *(uint4*)&wst[wm_][unit * 8] = *(const uint4*)&wrow[unit * 8];
                }
                __syncthreads();
            }
#pragma unroll
            for (int ks = 0; ks < 6; ++ks) {
                FragU afr[2];
#pragma unroll
                for (int mi = 0; mi < 2; ++mi) {
                    const int row = wm * 32 + mi * 16 + lm;
                    afr[mi].u4 = *(const uint4*)&wst[row][ks * 32 + g * 8];
                }
#pragma unroll
                for (int mi = 0; mi < 2; ++mi)
#pragma unroll
                    for (int nj = 0; nj < 4; ++nj)
                        acc[mb][mi][nj] = __builtin_amdgcn_mfma_f32_16x16x32_bf16(
                            afr[mi].s8, bfr[ks][nj].s8, acc[mb][mi][nj], 0, 0, 0);
            }
        }
    }
    // epilogue: bias + residual, fp32 out (16-lane x 4B = 64B segments, ok)
#pragma unroll
    for (int mb = 0; mb < 3; ++mb)
#pragma unroll
        for (int mi = 0; mi < 2; ++mi) {
            const int rbase = mb * 64 + wm * 32 + mi * 16 + g * 4;
            const float4 bv = *(const float4*)&bias[rbase];
            const float bva[4] = {bv.x, bv.y, bv.z, bv.w};
#pragma unroll
            for (int nj = 0; nj < 4; ++nj) {
                const int gcol = n0 + wn * 64 + nj * 16 + lm;
#pragma unroll
                for (int r = 0; r < 4; ++r) {
                    const size_t idx = ((size_t)b * DIMC + rbase + r) * NN + gcol;
                    out[idx] = resid[idx] + acc[mb][mi][nj][r] + bva[r];
                }
            }
        }
}

// ---------- depthwise 3x3 + bias, 8 px/thread ----------
__global__ __launch_bounds__(256) void k_dwconv2(
    const uint16_t* __restrict__ in, const float* __restrict__ w9,
    const float* __restrict__ bias, uint16_t* __restrict__ out)
{
    const int t = threadIdx.x;
    const int bc = blockIdx.z;
    const int ch = bc % D3;
    const int xg = t & 15, yl = t >> 4;
    const int x0 = xg * 8;
    const int y = blockIdx.y * 16 + yl;
    const uint16_t* p = in + (size_t)bc * NN;
    float wv[9];
#pragma unroll
    for (int k = 0; k < 9; ++k) wv[k] = w9[ch * 9 + k];
    float r[3][10];
#pragma unroll
    for (int dy = 0; dy < 3; ++dy) {
        const int yy = y + dy - 1;
        if (yy < 0 || yy >= HHGT) {
#pragma unroll
            for (int j = 0; j < 10; ++j) r[dy][j] = 0.f;
        } else {
            const uint16_t* row = p + yy * WWID;
            uint4 u = *(const uint4*)(row + x0);
            const uint16_t* pv = (const uint16_t*)&u;
#pragma unroll
            for (int j = 0; j < 8; ++j) r[dy][j + 1] = bf2f(pv[j]);
            r[dy][0] = (x0 > 0) ? bf2f(row[x0 - 1]) : 0.f;
            r[dy][9] = (x0 + 8 < WWID) ? bf2f(row[x0 + 8]) : 0.f;
        }
    }
    const float base = bias[ch];
    uint16_t ov[8];
#pragma unroll
    for (int j = 0; j < 8; ++j) {
        float a = base;
#pragma unroll
        for (int dy = 0; dy < 3; ++dy)
#pragma unroll
            for (int dx = 0; dx < 3; ++dx)
                a = fmaf(r[dy][j + dx], wv[dy * 3 + dx], a);
        ov[j] = f2bf(a);
    }
    *(uint4*)(out + (size_t)bc * NN + y * WWID + x0) = pack8(ov);
}

// ---------- MFMA scores + fused norm partials (NCK chunks) ----------
__global__ __launch_bounds__(256) void k_scores_mfma(
    const uint16_t* __restrict__ qkv_ms, const uint16_t* __restrict__ qkv_sar,
    float* __restrict__ partial, float* __restrict__ sumsq)
{
    const int t = threadIdx.x;
    const int bid = blockIdx.x;
    const int ck = bid & (NCK - 1);
    const int pid = bid / NCK;         // b*4 + h
    const int h = pid & 3, b = pid >> 2;
    const int n0 = ck * CKW;
    const int lane = t & 63, w = t >> 6;

    const uint16_t* qm  = qkv_ms  + ((size_t)b * D3 + h * CHD) * NN;
    const uint16_t* km  = qkv_ms  + ((size_t)b * D3 + DIMC + h * CHD) * NN;
    const uint16_t* qsr = qkv_sar + ((size_t)b * D3 + h * CHD) * NN;
    const uint16_t* ksr = qkv_sar + ((size_t)b * D3 + DIMC + h * CHD) * NN;

    if (w < 3) {
        const uint16_t* qb = (w == 0) ? qm : qsr;
        const uint16_t* kb = (w == 1) ? ksr : km;
        const int lm = lane & 15, g = lane >> 4;
        f32x4 acc[3][3];
#pragma unroll
        for (int i = 0; i < 3; ++i)
#pragma unroll
            for (int j = 0; j < 3; ++j) acc[i][j] = (f32x4){0.f, 0.f, 0.f, 0.f};
#pragma unroll 2
        for (int kk = 0; kk < CKW / 32; ++kk) {
            const int nb2 = n0 + kk * 32 + g * 8;
            FragU qf[3], kf[3];
#pragma unroll
            for (int i = 0; i < 3; ++i)
                qf[i].u4 = *(const uint4*)&qb[(size_t)(i * 16 + lm) * NN + nb2];
#pragma unroll
            for (int j = 0; j < 3; ++j)
                kf[j].u4 = *(const uint4*)&kb[(size_t)(j * 16 + lm) * NN + nb2];
#pragma unroll
            for (int i = 0; i < 3; ++i)
#pragma unroll
                for (int j = 0; j < 3; ++j)
                    acc[i][j] = __builtin_amdgcn_mfma_f32_16x16x32_bf16(
                        qf[i].s8, kf[j].s8, acc[i][j], 0, 0, 0);
        }
        float* pd = partial + (((size_t)pid * 3 + w) * NCK + ck) * 2304;
        const int g4 = g * 4;
#pragma unroll
        for (int i = 0; i < 3; ++i)
#pragma unroll
            for (int j = 0; j < 3; ++j)
#pragma unroll
                for (int r = 0; r < 4; ++r)
                    pd[(i * 16 + g4 + r) * 48 + j * 16 + lm] = acc[i][j][r];
    } else {
        // sumsq of 192 rows (0=q_ms 1=k_ms 2=q_sar 3=k_sar) over this chunk
#pragma unroll
        for (int rep = 0; rep < 3; ++rep) {
            const int rid = rep * 64 + lane;
            const int s = rid / CHD, c = rid % CHD;
            const uint16_t* rowp =
                (s == 0) ? qm  + (size_t)c * NN :
                (s == 1) ? km  + (size_t)c * NN :
                (s == 2) ? qsr + (size_t)c * NN :
                           ksr + (size_t)c * NN;
            float sum = 0.f;
#pragma unroll 4
            for (int u = 0; u < CKW / 8; ++u) {
                uint4 v = *(const uint4*)&rowp[n0 + u * 8];
                uint32_t uu[4] = {v.x, v.y, v.z, v.w};
#pragma unroll
                for (int q = 0; q < 4; ++q) {
                    float2 f = upk2(uu[q]);
                    sum = fmaf(f.x, f.x, fmaf(f.y, f.y, sum));
                }
            }
            sumsq[(((size_t)pid * NCK + ck) * 4 + s) * CHD + c] = sum;
        }
    }
}

// ---------- reduce chunks + norm scale + softmax ----------
__global__ __launch_bounds__(64) void k_softmax(
    const float* __restrict__ partial, const float* __restrict__ sumsq,
    const float* __restrict__ ms_temp, const float* __restrict__ sar_temp,
    float* __restrict__ A)
{
    const int lane = threadIdx.x;
    const int bi = blockIdx.x;
    const int c = bi % 48;
    const int pid = bi / 48;               // type*16 + b*4 + h
    const int h = pid & 3, b = (pid >> 2) & 3, type = pid >> 4;
    const int pid16 = b * 4 + h;
    float s;
    if (lane < 48) {
        float accv = 0.f;
        const float* pp = partial + ((size_t)pid16 * 3 + type) * NCK * 2304 + c * 48 + lane;
#pragma unroll 8
        for (int ck = 0; ck < NCK; ++ck) accv += pp[(size_t)ck * 2304];
        const int qset = (type == 0) ? 0 : 2;
        const int kset = (type == 1) ? 3 : 1;
        float qsum = 0.f, ksum = 0.f;
        const float* sq = sumsq + (size_t)pid16 * NCK * 4 * CHD;
#pragma unroll 8
        for (int ck = 0; ck < NCK; ++ck) {
            qsum += sq[ck * 4 * CHD + qset * CHD + c];
            ksum += sq[ck * 4 * CHD + kset * CHD + lane];
        }
        const float tval = (type == 1) ? sar_temp[h] : ms_temp[h];
        const float qsc = 1.0f / fmaxf(sqrtf(qsum), 1e-12f);
        const float ksc = 1.0f / fmaxf(sqrtf(ksum), 1e-12f);
        s = accv * qsc * ksc * tval;
    } else {
        s = -3.0e38f;
    }
    float m = s;
#pragma unroll
    for (int o = 32; o > 0; o >>= 1) m = fmaxf(m, __shfl_xor(m, o));
    float e = (lane < 48) ? __expf(s - m) : 0.f;
    float sum = e;
#pragma unroll
    for (int o = 32; o > 0; o >>= 1) sum += __shfl_xor(sum, o);
    if (lane < 48) A[(size_t)pid * 2304 + c * 48 + lane] = e / sum;
}

// ---------- MFMA apply: out[c][n] = sum_d A[c][d] V[d][n] ----------
// NEW: coalesced bf16 epilogue via wave-private LDS scratch.
__global__ __launch_bounds__(256) void k_apply_mfma(
    const float* __restrict__ A, const uint16_t* __restrict__ qkv_ms,
    const uint16_t* __restrict__ qkv_sar, uint16_t* __restrict__ attn)
{
    __shared__ uint16_t vs[256][40];
    __shared__ uint16_t as[48][40];
    __shared__ uint16_t sw_all[4][48][72];
    const int t = threadIdx.x;
    const int nb = blockIdx.x & 63;
    const int pid = blockIdx.x >> 6;
    const int h = pid & 3, b = (pid >> 2) & 3, type = pid >> 4;
    const int n0 = nb * 256;
    const uint16_t* vsrc = (type == 0) ? qkv_ms : qkv_sar;
    const uint16_t* vb = vsrc + ((size_t)b * D3 + 2 * DIMC + (size_t)h * CHD) * NN;
    const float* Ap = A + (size_t)pid * 2304;

    const int lane = t & 63, wvid = t >> 6;
    const int lm = lane & 15, g = lane >> 4;

    f32x4 acc[3][4];
#pragma unroll
    for (int i = 0; i < 3; ++i)
#pragma unroll
        for (int j = 0; j < 4; ++j) acc[i][j] = (f32x4){0.f, 0.f, 0.f, 0.f};

    for (int k0 = 0; k0 < 64; k0 += 32) {
        __syncthreads();
#pragma unroll
        for (int kh = 0; kh < 2; ++kh) {
            uint16_t vals[16];
#pragma unroll
            for (int j = 0; j < 16; ++j) {
                const int d = k0 + kh * 16 + j;
                vals[j] = (d < CHD) ? vb[(size_t)d * NN + n0 + t] : (uint16_t)0;
            }
            const int u0 = (2 * kh) ^ ((t >> 3) & 3);
            const int u1 = (2 * kh + 1) ^ ((t >> 3) & 3);
            *(uint4*)&vs[t][u0 * 8] = pack8(&vals[0]);
            *(uint4*)&vs[t][u1 * 8] = pack8(&vals[8]);
        }
        if (t < 192) {
            const int c = t >> 2, dq = t & 3;
            uint16_t av[8];
#pragma unroll
            for (int i = 0; i < 8; ++i) {
                const int d = k0 + dq * 8 + i;
                av[i] = (d < CHD) ? f2bf(Ap[c * CHD + d]) : (uint16_t)0;
            }
            const int u = dq ^ ((c >> 3) & 3);
            *(uint4*)&as[c][u * 8] = pack8(av);
        }
        __syncthreads();
        FragU afr[3], bfr[4];
#pragma unroll
        for (int mi = 0; mi < 3; ++mi) {
            const int row = mi * 16 + lm;
            afr[mi].u4 = *(const uint4*)&as[row][(g ^ ((row >> 3) & 3)) * 8];
        }
#pragma unroll
        for (int nj = 0; nj < 4; ++nj) {
            const int row = wvid * 64 + nj * 16 + lm;
            bfr[nj].u4 = *(const uint4*)&vs[row][(g ^ ((row >> 3) & 3)) * 8];
        }
#pragma unroll
        for (int mi = 0; mi < 3; ++mi)
#pragma unroll
            for (int nj = 0; nj < 4; ++nj)
                acc[mi][nj] = __builtin_amdgcn_mfma_f32_16x16x32_bf16(
                    afr[mi].s8, bfr[nj].s8, acc[mi][nj], 0, 0, 0);
    }

    uint16_t* ob = attn + (size_t)type * BB * DIMC * NN +
                   ((size_t)b * DIMC + (size_t)h * CHD) * NN;
    uint16_t* sw = &sw_all[wvid][0][0];
#pragma unroll
    for (int mi = 0; mi < 3; ++mi)
#pragma unroll
        for (int nj = 0; nj < 4; ++nj)
#pragma unroll
            for (int r = 0; r < 4; ++r)
                sw[(mi * 16 + g * 4 + r) * 72 + nj * 16 + lm] = f2bf(acc[mi][nj][r]);
    const int l8 = lane & 7, r8 = lane >> 3;
#pragma unroll
    for (int pass = 0; pass < 6; ++pass) {
        const int rr = pass * 8 + r8;
        uint4 v = *(const uint4*)&sw[rr * 72 + l8 * 8];
        *(uint4*)&ob[(size_t)rr * NN + n0 + wvid * 64 + l8 * 8] = v;
    }
}

extern "C" void kernel_launch(void* const* d_in, const int* in_sizes, int n_in,
                              void* d_out, int out_size, void* d_ws, size_t ws_size,
                              hipStream_t stream)
{
    const float* sar        = (const float*)d_in[0];
    const float* ms         = (const float*)d_in[1];
    const float* ms_qkv_w   = (const float*)d_in[2];
    const float* ms_qkv_b   = (const float*)d_in[3];
    const float* ms_dw_w    = (const float*)d_in[4];
    const float* ms_dw_b    = (const float*)d_in[5];
    const float* ms_temp    = (const float*)d_in[6];
    const float* sar_qkv_w  = (const float*)d_in[7];
    const float* sar_qkv_b  = (const float*)d_in[8];
    const float* sar_dw_w   = (const float*)d_in[9];
    const float* sar_dw_b   = (const float*)d_in[10];
    const float* sar_temp   = (const float*)d_in[11];
    const float* ms_proj_w  = (const float*)d_in[12];
    const float* ms_proj_b  = (const float*)d_in[13];
    const float* sar_proj_w = (const float*)d_in[14];
    const float* sar_proj_b = (const float*)d_in[15];

    char* ws = (char*)d_ws;
    // ws layout (bytes):
    //   [0,          75497472)  tmp bf16 (conv1x1 out) -> score partials scratch
    //                           -> finally attn outputs (written by apply)
    //     partial: 16pid x 3type x 64ck x 2304 f32 = 28.3 MB at +0
    //     sumsq:   16pid x 64ck x 4set x 48  f32 = 0.79 MB at +32MB
    //   [75497472,  150994944)  qkv_ms bf16
    //   [150994944, 226492416)  qkv_sar bf16
    //   [230043648, 230486016)  softmaxed A f32
    //   [230486016, 231149568)  bf16 weights
    uint16_t* tmp     = (uint16_t*)(ws);
    uint16_t* qkv_ms  = (uint16_t*)(ws + 75497472ull);
    uint16_t* qkv_sar = (uint16_t*)(ws + 150994944ull);
    float* partial    = (float*)(ws);
    float* sumsq      = (float*)(ws + 33554432ull);
    float* Amat       = (float*)(ws + 230043648ull);
    uint16_t* wq_ms   = (uint16_t*)(ws + 230486016ull);
    uint16_t* wq_sar  = (uint16_t*)(ws + 230707200ull);
    uint16_t* wp1_ms  = (uint16_t*)(ws + 230928384ull);
    uint16_t* wp2_ms  = (uint16_t*)(ws + 231002112ull);
    uint16_t* wp_sar  = (uint16_t*)(ws + 231075840ull);
    uint16_t* attn    = tmp;

    float* out_sar = (float*)d_out;
    float* out_ms  = out_sar + (size_t)BB * DIMC * NN;

    dim3 b256(256);
    k_prep<<<dim3(1152), b256, 0, stream>>>(ms_qkv_w, sar_qkv_w, ms_proj_w, sar_proj_w,
                                            wq_ms, wq_sar, wp1_ms, wp2_ms, wp_sar);
    k_conv_mfma<<<dim3(128 * BB), b256, 0, stream>>>(ms, wq_ms, ms_qkv_b, tmp);
    k_dwconv2<<<dim3(1, 8, BB * D3), b256, 0, stream>>>(tmp, ms_dw_w, ms_dw_b, qkv_ms);
    k_conv_mfma<<<dim3(128 * BB), b256, 0, stream>>>(sar, wq_sar, sar_qkv_b, tmp);
    k_dwconv2<<<dim3(1, 8, BB * D3), b256, 0, stream>>>(tmp, sar_dw_w, sar_dw_b, qkv_sar);

    k_scores_mfma<<<dim3(16 * NCK), b256, 0, stream>>>(qkv_ms, qkv_sar, partial, sumsq);
    k_softmax<<<dim3(48 * 48), dim3(64), 0, stream>>>(partial, sumsq, ms_temp, sar_temp, Amat);
    k_apply_mfma<<<dim3(48 * 64), b256, 0, stream>>>(Amat, qkv_ms, qkv_sar, attn);

    uint16_t* ms_self  = attn;
    uint16_t* sar_self = attn + (size_t)BB * DIMC * NN;
    uint16_t* crossb   = attn + 2ull * BB * DIMC * NN;
    k_proj_mfma<1><<<dim3(128 * BB), b256, 0, stream>>>(
        sar_self, nullptr, wp_sar, nullptr, sar_proj_b, sar, out_sar);
    k_proj_mfma<2><<<dim3(128 * BB), b256, 0, stream>>>(
        ms_self, crossb, wp1_ms, wp2_ms, ms_proj_b, ms, out_ms);
}